// Round 7
// baseline (428.790 us; speedup 1.0000x reference)
//
#include <hip/hip_runtime.h>
#include <hip/hip_bf16.h>

#define N_NODES 50000
#define N_EDGES 800000
#define D_IN    16
#define D_HID   64
#define D_OUT   16
#define NCHUNK  ((N_NODES + 255) / 256)   // 196 scan chunks
#define TMAX    100352                    // >= worst-case padded tile count
#define GE8     ((N_EDGES / 8 + 255) / 256)      // 391 blocks (8 edges/thread)
#define GH      ((N_NODES * D_HID + 255) / 256)  // 12500 blocks
#define SCAP    48                        // slots per node (3 tiles)
#define NB      98                        // scatter buckets (512 nodes each)
#define BCAP    12288                     // edges per bucket capacity

typedef __hip_bfloat16 bf16;
typedef _Float16 f16;
typedef _Float16 f16x8 __attribute__((ext_vector_type(8)));
typedef _Float16 f16x4 __attribute__((ext_vector_type(4)));
typedef float    f32x4 __attribute__((ext_vector_type(4)));
typedef _Float16 f16x8a __attribute__((ext_vector_type(8), may_alias));
typedef _Float16 f16x4a __attribute__((ext_vector_type(4), may_alias));
typedef unsigned short u16x8a __attribute__((ext_vector_type(8), may_alias));
typedef float    f32x4a __attribute__((ext_vector_type(4), may_alias));

__device__ __forceinline__ float b2f(bf16 v) { return __bfloat162float(v); }
__device__ __forceinline__ float bfb(unsigned short u) {
    union { unsigned u; float f; } z; z.u = (unsigned)u << 16; return z.f;
}
__device__ __forceinline__ int clampn(int v) {
    return v < 0 ? 0 : (v >= N_NODES ? N_NODES - 1 : v);
}
__device__ __forceinline__ float rdf(const void* p, long i, int isbf) {
    return isbf ? b2f(((const bf16*)p)[i]) : ((const float*)p)[i];
}
__device__ __forceinline__ f16x8 relu8(f16x8 v) {
#pragma unroll
    for (int j = 0; j < 8; j++) v[j] = v[j] > (f16)0 ? v[j] : (f16)0;
    return v;
}
__device__ __forceinline__ f16x4 relu4(f16x4 v) {
#pragma unroll
    for (int j = 0; j < 4; j++) v[j] = v[j] > (f16)0 ? v[j] : (f16)0;
    return v;
}
// tile slot base (u16 element index) from packed tmeta (n | valid<<20 | j<<25)
__device__ __forceinline__ int sbase(int m) {
    return (m & 0xFFFFF) * SCAP + ((m >> 25) & 3) * 16;
}

// ---------------------------------------------------------------------------
// k_detect (1 block): dtype flags + Psrc dummy -inf row + zero bucket cnts.
// ---------------------------------------------------------------------------
__global__ __launch_bounds__(256) void k_detect(const unsigned short* __restrict__ xw,
                                                const int* __restrict__ ei,
                                                int* __restrict__ flags,
                                                int* __restrict__ gbcnt,
                                                unsigned short* __restrict__ psrc_us)
{
    const int t = threadIdx.x;
    if (t < 64) psrc_us[(size_t)N_NODES * 64 + t] = 0xFC00u;   // f16 -inf
    if (t < NB) gbcnt[t] = 0;
    if (t == 0) {
        int inband = 0;
        for (int j = 0; j < 256; j++) {
            unsigned short w = xw[2 * j];
            int e = (w >> 7) & 0xFF;
            if ((w & 0x7FFF) == 0 || (e >= 100 && e <= 140)) inband++;
        }
        flags[0] = (inband >= 192) ? 1 : 0;
        int z = 1;
        for (int j = 1; j < 128; j += 2) z &= (ei[j] == 0) ? 1 : 0;
        flags[1] = z;
    }
}

// ---------------------------------------------------------------------------
// Fused prep (R25-verified): wprep + bucketed phase-1 scatter + lin_in + cpad
// ---------------------------------------------------------------------------
__global__ __launch_bounds__(256) void k_prep(const int* __restrict__ flags,
                                              const void* __restrict__ gw0,
                                              const void* __restrict__ gw1,
                                              const void* __restrict__ gw2,
                                              f16* __restrict__ wfrag,
                                              const int* __restrict__ eidx,
                                              int* __restrict__ gbcnt,
                                              unsigned int* __restrict__ gbuckets,
                                              const void* __restrict__ x,
                                              const void* __restrict__ liw,
                                              const void* __restrict__ lib,
                                              float* __restrict__ h,
                                              const void* __restrict__ gb1,
                                              const void* __restrict__ gb2,
                                              float* __restrict__ cpad)
{
    const int isbf = flags[0];
    const int bid = blockIdx.x;
    if (bid < 32) {
        // ---- weight prep ----
        int idx = bid * 256 + threadIdx.x;      // [0, 8192)
        int kb = idx >> 11, rem = idx & 2047;
        int slot = rem >> 6, lane = rem & 63;
        int lm = lane & 15, quad = lane >> 4;
        f16* outp = wfrag + (long)idx * 8;
        if (slot < 16) {
            int c = slot >> 2, q = slot & 3;
            long base = (long)kb * 2 * D_HID * D_HID;
#pragma unroll
            for (int j = 0; j < 8; j++)
                outp[j] = (f16)rdf(gw0, base + (long)(c * 32 + quad * 8 + j) * 64 + q * 16 + lm, isbf);
        } else {
            const void* gw = (slot < 24) ? gw1 : gw2;
            int s = (slot < 24) ? slot - 16 : slot - 24;
            int c = s >> 2, q = s & 3;
            long base = (long)kb * D_HID * D_HID;
#pragma unroll
            for (int j = 0; j < 8; j++)
                outp[j] = (f16)rdf(gw, base + (long)(c * 32 + quad * 8 + j) * 64 + q * 16 + lm, isbf);
        }
    } else if (bid < 32 + GE8) {
        // ---- phase-1 bucket scatter (NO early return: block barriers) ----
        __shared__ int cnt[NB], base[NB];
        const int t = threadIdx.x;
        for (int k = t; k < NB; k += 256) cnt[k] = 0;
        __syncthreads();
        const int ebase = ((bid - 32) * 256 + t) * 8;
        const int cntv = (ebase < N_EDGES) ? min(8, N_EDGES - ebase) : 0;
        const int strd = flags[1] ? 2 : 1;
        const long dbase = flags[1] ? (long)(2 * N_EDGES) : (long)N_EDGES;
        int d[8], s[8], r[8];
#pragma unroll
        for (int j = 0; j < 8; j++)
            if (j < cntv) {
                d[j] = clampn(eidx[dbase + (long)(ebase + j) * strd]);
                s[j] = clampn(eidx[(long)(ebase + j) * strd]);
            }
#pragma unroll
        for (int j = 0; j < 8; j++)
            if (j < cntv) r[j] = atomicAdd(&cnt[d[j] >> 9], 1);
        __syncthreads();
        for (int k = t; k < NB; k += 256)
            base[k] = cnt[k] ? atomicAdd(&gbcnt[k], cnt[k]) : 0;
        __syncthreads();
#pragma unroll
        for (int j = 0; j < 8; j++)
            if (j < cntv) {
                int b = d[j] >> 9;
                int p = base[b] + r[j];
                if (p < BCAP)
                    gbuckets[(size_t)b * BCAP + p] =
                        ((unsigned)(d[j] & 511) << 16) | (unsigned)s[j];
            }
    } else if (bid < 32 + GE8 + GH) {
        // ---- lin_in (vectorized) ----
        int idx = (bid - 32 - GE8) * 256 + threadIdx.x;
        if (idx >= N_NODES * D_HID) return;
        int n = idx >> 6, c = idx & 63;
        float acc, wr[16], xr[16];
        if (isbf) {
            const unsigned short* xp = (const unsigned short*)x + (long)n * 16;
            u16x8a x0 = *(const u16x8a*)xp, x1 = *(const u16x8a*)(xp + 8);
#pragma unroll
            for (int i = 0; i < 8; i++) { xr[i] = bfb(x0[i]); xr[8 + i] = bfb(x1[i]); }
            const unsigned short* wq = (const unsigned short*)liw;
#pragma unroll
            for (int i = 0; i < 16; i++) wr[i] = bfb(wq[i * 64 + c]);
            acc = bfb(((const unsigned short*)lib)[c]);
        } else {
            const float* xp = (const float*)x + (long)n * 16;
#pragma unroll
            for (int q = 0; q < 4; q++) {
                f32x4a v = *(const f32x4a*)(xp + q * 4);
#pragma unroll
                for (int j = 0; j < 4; j++) xr[q * 4 + j] = v[j];
            }
            const float* wq = (const float*)liw;
#pragma unroll
            for (int i = 0; i < 16; i++) wr[i] = wq[i * 64 + c];
            acc = ((const float*)lib)[c];
        }
#pragma unroll
        for (int i = 0; i < 16; i++) acc += xr[i] * wr[i];
        h[idx] = acc;
    } else {
        // ---- c_pad: mirror the f16 MFMA quantization path exactly ----
        int t = threadIdx.x;                  // 256 = 4 kblk x 64 feats
        int k = t >> 6, j = t & 63;
        float acc = rdf(gb2, (long)k * 64 + j, isbf);
        for (int i = 0; i < 64; i++) {
            float zi = (float)(f16)fmaxf(rdf(gb1, (long)k * 64 + i, isbf), 0.f);
            float wi = (float)(f16)rdf(gw2, (long)k * 4096 + (long)i * 64 + j, isbf);
            acc += zi * wi;
        }
        cpad[k * 64 + j] = acc;
    }
}

// ---------------------------------------------------------------------------
// phase-2: per-bucket LDS slot build + degrees + chunk tile sums.
// ---------------------------------------------------------------------------
__global__ __launch_bounds__(256) void k_bucket(const int* __restrict__ gbcnt,
                                                const unsigned int* __restrict__ gbuckets,
                                                unsigned short* __restrict__ slots,
                                                int* __restrict__ deg,
                                                int* __restrict__ bsum_t)
{
    __shared__ unsigned short sl[512 * SCAP];   // 49152 B
    __shared__ int cur[512];
    __shared__ int red[256];
    const int t = threadIdx.x, b = blockIdx.x;

    for (int k = t; k < 512; k += 256) cur[k] = 0;
    unsigned int* sl32 = (unsigned int*)sl;
    for (int k = t; k < 512 * SCAP / 2; k += 256) sl32[k] = 0xC350C350u;  // dummy id
    __syncthreads();

    const int ne = min(gbcnt[b], BCAP);
    const unsigned int* eb = gbuckets + (size_t)b * BCAP;
    for (int k = t; k < ne; k += 256) {
        unsigned int rec = eb[k];
        int n = rec >> 16;
        int pos = atomicAdd(&cur[n], 1);
        if (pos < SCAP) sl[n * SCAP + pos] = (unsigned short)(rec & 0xFFFFu);
    }
    __syncthreads();

    const int n0 = b * 512;
    const int nn = min(512, N_NODES - n0);
    // coalesced slot writeout (u32)
    unsigned int* gs32 = (unsigned int*)slots;
    for (int k = t; k < nn * SCAP / 2; k += 256)
        gs32[(size_t)n0 * SCAP / 2 + k] = sl32[k];
    // degrees + per-chunk tile sums (2 chunks of 256 nodes per bucket)
    for (int half = 0; half < 2; half++) {
        int n = half * 256 + t;
        int dv = (n < nn) ? cur[n] : 0;
        if (n < nn) deg[n0 + n] = dv;
        red[t] = min((dv + 15) >> 4, 3);
        __syncthreads();
        for (int d2 = 128; d2 > 0; d2 >>= 1) {
            if (t < d2) red[t] += red[t + d2];
            __syncthreads();
        }
        if (t == 0) bsum_t[b * 2 + half] = red[0];
        __syncthreads();
    }
}

__global__ __launch_bounds__(256) void k_scan2(const int* __restrict__ bsum_t,
                                               int* __restrict__ boff_t,
                                               int* __restrict__ tot_t)
{
    __shared__ int st_[256];
    const int t = threadIdx.x;
    st_[t] = (t < NCHUNK) ? bsum_t[t] : 0;
    __syncthreads();
    for (int d = 1; d < 256; d <<= 1) {
        int vt = (t >= d) ? st_[t - d] : 0;
        __syncthreads();
        st_[t] += vt;
        __syncthreads();
    }
    if (t < NCHUNK) boff_t[t] = (t == 0) ? 0 : st_[t - 1];
    if (t == NCHUNK - 1) tot_t[0] = st_[t];
}

// final scan stage + tmeta emission: tmeta[t] = node | valid<<20 | j<<25
__global__ __launch_bounds__(256) void k_scan3(const int* __restrict__ deg,
                                               const int* __restrict__ boff_t,
                                               int* __restrict__ toff,
                                               int* __restrict__ tmeta)
{
    __shared__ int st_[256];
    const int t = threadIdx.x;
    int i = blockIdx.x * 256 + t;
    int v = (i < N_NODES) ? deg[i] : 0;
    int w = min((v + 15) >> 4, 3);
    st_[t] = w;
    __syncthreads();
    for (int d = 1; d < 256; d <<= 1) {
        int ut = (t >= d) ? st_[t - d] : 0;
        __syncthreads();
        st_[t] += ut;
        __syncthreads();
    }
    if (i < N_NODES) {
        int exT = boff_t[blockIdx.x] + st_[t] - w;
        toff[i] = exT;
        for (int j = 0; j < w; j++)
            tmeta[exT + j] = i | (min(16, v - 16 * j) << 20) | (j << 25);
    }
}

// ---------------------------------------------------------------------------
// Node projection (R17-verified). Zero-in-degree nodes zeroed here.
// ---------------------------------------------------------------------------
#define HP_ST 72

__global__ __launch_bounds__(256) void k_proj(
    const int* __restrict__ flags, float* hio,
    const f16* __restrict__ wfrag, const void* __restrict__ gb0,
    const int* __restrict__ deg,
    f16* __restrict__ psrc, f16* __restrict__ pdst, int kblk)
{
    __shared__ f16 hL_s[4][16 * HP_ST];     // 9216 B

    const int tid  = threadIdx.x;
    const int isbf = flags[0];
    const int wv = tid >> 6, ln = tid & 63;
    const int lm = ln & 15, quad = ln >> 4;
    f16* hL = hL_s[wv];

    const int g = blockIdx.x * 4 + wv;
    if (g >= N_NODES / 16) return;
    const int n0 = g * 16;

    const f16* wb = wfrag + (long)kblk * 32 * 64 * 8;

#pragma unroll
    for (int i = 0; i < 16; i++) {
        int idx = i * 64 + ln;
        hL[(idx >> 6) * HP_ST + (idx & 63)] = (f16)hio[(long)n0 * 64 + idx];
    }
    // zero-in-degree nodes are never stored by the aggregation — zero their
    // rows so next proj / lin_out read segment_sum = 0
#pragma unroll
    for (int i = 0; i < 16; i++)
        if (deg[n0 + i] == 0) hio[(long)(n0 + i) * 64 + ln] = 0.f;

    f16x8 a[2];
#pragma unroll
    for (int c = 0; c < 2; c++)
        a[c] = *(const f16x8a*)&hL[lm * HP_ST + c * 32 + quad * 8];

    f32x4 accS[4], accD[4];
#pragma unroll
    for (int q = 0; q < 4; q++) {
        float bd = rdf(gb0, (long)kblk * 64 + q * 16 + lm, isbf);
        accS[q] = (f32x4){0.f, 0.f, 0.f, 0.f};
        accD[q] = (f32x4){bd, bd, bd, bd};
    }
#pragma unroll
    for (int c = 0; c < 2; c++)
#pragma unroll
        for (int q = 0; q < 4; q++) {
            f16x8 bs = *(const f16x8a*)&wb[(((c + 0) * 4 + q) * 64 + ln) * 8];
            f16x8 bd = *(const f16x8a*)&wb[(((c + 2) * 4 + q) * 64 + ln) * 8];
            accS[q] = __builtin_amdgcn_mfma_f32_16x16x32_f16(a[c], bs, accS[q], 0, 0, 0);
            accD[q] = __builtin_amdgcn_mfma_f32_16x16x32_f16(a[c], bd, accD[q], 0, 0, 0);
        }
#pragma unroll
    for (int q = 0; q < 4; q++)
#pragma unroll
        for (int r = 0; r < 4; r++) {
            long o = (long)(n0 + quad * 4 + r) * 64 + q * 16 + lm;
            psrc[o] = (f16)accS[q][r];
            pdst[o] = (f16)accD[q][r];
        }
}

// ---------------------------------------------------------------------------
// ROUND-26 aggregation: CROSS-TILE SOFTWARE PIPELINE.
// The 52us duration was invariant across VALU/TLP changes (R0/R3/R6) ->
// bound is the per-tile dependency chain (5 dependent LDS round trips).
// Split: iteration tt runs layer0+layer1 of tile tt (write y-buf W) and
// layer2 of tile tt-1 (read y-buf R, written last iteration). The a2 read
// issues at the TOP of the iteration with a full iteration of slack, and
// layer2's 8 MFMAs become overlap work for the layer0->a1 stall.
// Flush uses delayed meta mP. Everything else R24/R25-verified.
// ---------------------------------------------------------------------------
#define Y_ST 72

__global__ __launch_bounds__(256) void k_edge_tile(
    const int* __restrict__ flags,
    const unsigned short* __restrict__ slots, const int* __restrict__ tmeta,
    const int* __restrict__ toff,
    const f16* __restrict__ psrc, const f16* __restrict__ pdst,
    float* __restrict__ hout,
    const f16* __restrict__ wfrag, const void* __restrict__ gb1,
    const void* __restrict__ gb2, const float* __restrict__ cpad, int kblk)
{
    __shared__ f16 y_s[4][2][16 * Y_ST];   // 18432 B (double-buffered per wave)
    __shared__ float b1L[64], b2L[64], cpL[64];

    const int tid  = threadIdx.x;
    const int isbf = flags[0];
    const int wv = tid >> 6, ln = tid & 63;
    const int lm = ln & 15, quad = ln >> 4;
    const int sub = ln & 7, eh = ln >> 3;

    // stage biases + cpad (once per block)
    if (tid < 64)       b1L[tid]       = rdf(gb1, (long)kblk * 64 + tid, isbf);
    else if (tid < 128) b2L[tid - 64]  = rdf(gb2, (long)kblk * 64 + (tid - 64), isbf);
    else if (tid < 192) cpL[tid - 128] = cpad[kblk * 64 + (tid - 128)];
    __syncthreads();

    const f16* wb = wfrag + (long)kblk * 32 * 64 * 8;
    f16x8 bw1[2][4], bw2[2][4];
#pragma unroll
    for (int c = 0; c < 2; c++)
#pragma unroll
        for (int q = 0; q < 4; q++) {
            bw1[c][q] = *(const f16x8a*)&wb[((16 + c * 4 + q) * 64 + ln) * 8];
            bw2[c][q] = *(const f16x8a*)&wb[((24 + c * 4 + q) * 64 + ln) * 8];
        }

    const int T  = toff[N_NODES];
    const int W  = gridDim.x * 4;
    const int gw = blockIdx.x * 4 + wv;
    int t0 = (int)((long)gw * T / W);
    int t1 = (int)((long)(gw + 1) * T / W);
    // node-aligned ownership (exact partition of [0, T))
    if (t0 > 0)
        while (t0 < T && (tmeta[t0] & 0xFFFFF) == (tmeta[t0 - 1] & 0xFFFFF)) t0++;
    if (t1 > 0)
        while (t1 < T && (tmeta[t1] & 0xFFFFF) == (tmeta[t1 - 1] & 0xFFFFF)) t1++;
    if (t0 >= t1) return;

    f16* yW = y_s[wv][0];
    f16* yR = y_s[wv][1];

    // ---- pipeline prologue: meta t0..t0+2, slot idx t0..t0+1, data t0 ----
    int mA = tmeta[t0];
    int mB = tmeta[min(t0 + 1, T - 1)];
    int mC = tmeta[min(t0 + 2, T - 1)];
    int mP = 0;                            // meta of tile tt-1 (valid tt>t0)
    int bA = sbase(mA), bB = sbase(mB);
    int sAa = slots[bA + eh], sAb = slots[bA + 8 + eh];
    int sBa = slots[bB + eh], sBb = slots[bB + 8 + eh];
    f16x8 psAa = *(const f16x8a*)&psrc[(long)sAa * 64 + sub * 8];
    f16x8 psAb = *(const f16x8a*)&psrc[(long)sAb * 64 + sub * 8];
    f16x8 pdA  = *(const f16x8a*)&pdst[(long)(mA & 0xFFFFF) * 64 + sub * 8];

    f32x4 accv[4];
#pragma unroll
    for (int q = 0; q < 4; q++) accv[q] = (f32x4){0.f, 0.f, 0.f, 0.f};

    for (int tt = t0; tt < t1; ++tt) {
        const bool hasP = (tt > t0);
        // ---- EARLY: a2 read for tile tt-1 from yR (written last iter) ----
        f16x8 a2[2];
        if (hasP) {
            a2[0] = *(const f16x8a*)&yR[lm * Y_ST + quad * 8];
            a2[1] = *(const f16x8a*)&yR[lm * Y_ST + 32 + quad * 8];
        }

        // ---- prefetch meta tt+3, slot idx tt+2, data tt+1 ----
        const int mD = tmeta[min(tt + 3, T - 1)];
        const int bC = sbase(mC);
        const int sCa = slots[bC + eh], sCb = slots[bC + 8 + eh];
        f16x8 psBa = *(const f16x8a*)&psrc[(long)sBa * 64 + sub * 8];
        f16x8 psBb = *(const f16x8a*)&psrc[(long)sBb * 64 + sub * 8];
        f16x8 pdB  = *(const f16x8a*)&pdst[(long)(mB & 0xFFFFF) * 64 + sub * 8];

        // ---- layer 0 of tile tt (pad rows: -inf + pd -> relu -> 0) ----
        *(f16x8a*)&yW[eh * Y_ST + sub * 8]       = relu8(psAa + pdA);
        *(f16x8a*)&yW[(8 + eh) * Y_ST + sub * 8] = relu8(psAb + pdA);

        // ---- layer 1 of tile tt (operand-swapped; C init from b1L) ----
        f16x8 a1[2];
        a1[0] = *(const f16x8a*)&yW[lm * Y_ST + quad * 8];
        a1[1] = *(const f16x8a*)&yW[lm * Y_ST + 32 + quad * 8];
        f32x4 acc1[4];
#pragma unroll
        for (int q = 0; q < 4; q++)
            acc1[q] = *(const f32x4a*)&b1L[q * 16 + quad * 4];
#pragma unroll
        for (int c = 0; c < 2; c++)
#pragma unroll
            for (int q = 0; q < 4; q++)
                acc1[q] = __builtin_amdgcn_mfma_f32_16x16x32_f16(bw1[c][q], a1[c], acc1[q], 0, 0, 0);
        // transposed output -> packed b64 writes to yW[e=lm][n]
#pragma unroll
        for (int q = 0; q < 4; q++) {
            f16x4 pk = { (f16)acc1[q][0], (f16)acc1[q][1],
                         (f16)acc1[q][2], (f16)acc1[q][3] };
            *(f16x4a*)&yW[lm * Y_ST + q * 16 + quad * 4] = relu4(pk);
        }

        // ---- layer 2 of tile tt-1 (accumulate in MFMA C) + flush ----
        if (hasP) {
#pragma unroll
            for (int c = 0; c < 2; c++)
#pragma unroll
                for (int q = 0; q < 4; q++)
                    accv[q] = __builtin_amdgcn_mfma_f32_16x16x32_f16(a2[c], bw2[c][q], accv[q], 0, 0, 0);
            const int curn = mP & 0xFFFFF;
            const int nxt  = mA & 0xFFFFF;
            if (nxt != curn) {
                const float npad = (float)(16 - ((mP >> 20) & 31));
                const float nt16 = (float)((((mP >> 25) & 3) + 1) * 16);
#pragma unroll
                for (int q = 0; q < 4; q++) {
                    float v = accv[q][0] + accv[q][1] + accv[q][2] + accv[q][3];
                    v += __shfl_xor(v, 16, 64);
                    v += __shfl_xor(v, 32, 64);
                    if (quad == 0) {
                        const int f = q * 16 + lm;
                        hout[(long)curn * 64 + f] = v + nt16 * b2L[f] - npad * cpL[f];
                    }
                    accv[q] = (f32x4){0.f, 0.f, 0.f, 0.f};
                }
            }
        }

        // ---- rotate pipeline ----
        mP = mA; mA = mB; mB = mC; mC = mD;
        sBa = sCa; sBb = sCb;
        psAa = psBa; psAb = psBb; pdA = pdB;
        f16* ytmp = yW; yW = yR; yR = ytmp;
    }

    // ---- epilogue: layer2 of tile t1-1 (meta mP) + unconditional flush ----
    {
        f16x8 a2[2];
        a2[0] = *(const f16x8a*)&yR[lm * Y_ST + quad * 8];
        a2[1] = *(const f16x8a*)&yR[lm * Y_ST + 32 + quad * 8];
#pragma unroll
        for (int c = 0; c < 2; c++)
#pragma unroll
            for (int q = 0; q < 4; q++)
                accv[q] = __builtin_amdgcn_mfma_f32_16x16x32_f16(a2[c], bw2[c][q], accv[q], 0, 0, 0);
        const int curn = mP & 0xFFFFF;
        const float npad = (float)(16 - ((mP >> 20) & 31));
        const float nt16 = (float)((((mP >> 25) & 3) + 1) * 16);
#pragma unroll
        for (int q = 0; q < 4; q++) {
            float v = accv[q][0] + accv[q][1] + accv[q][2] + accv[q][3];
            v += __shfl_xor(v, 16, 64);
            v += __shfl_xor(v, 32, 64);
            if (quad == 0) {
                const int f = q * 16 + lm;
                hout[(long)curn * 64 + f] = v + nt16 * b2L[f] - npad * cpL[f];
            }
        }
    }
}

// ---------------------------------------------------------------------------
// lin_out: W/b staged in LDS once per block, float4 h loads.
// ---------------------------------------------------------------------------
__global__ __launch_bounds__(256) void k_lin_out(const int* __restrict__ flags,
                                                 const float* __restrict__ h,
                                                 const void* __restrict__ w,
                                                 const void* __restrict__ b,
                                                 float* __restrict__ out)
{
    __shared__ float wl[D_HID * D_OUT];   // 4 KB
    __shared__ float bl[D_OUT];
    const int isbf = flags[0];
    const int t = threadIdx.x;
    for (int k = t; k < D_HID * D_OUT; k += 256) wl[k] = rdf(w, k, isbf);
    if (t < D_OUT) bl[t] = rdf(b, t, isbf);
    __syncthreads();

    int idx = blockIdx.x * 256 + t;
    if (idx >= N_NODES * D_OUT) return;
    int n = idx >> 4, c = idx & 15;
    const float* hr = h + (long)n * D_HID;
    float acc = bl[c];
#pragma unroll
    for (int i = 0; i < 16; i++) {
        f32x4a v = *(const f32x4a*)(hr + i * 4);
        acc += v[0] * wl[(i * 4 + 0) * 16 + c] + v[1] * wl[(i * 4 + 1) * 16 + c]
             + v[2] * wl[(i * 4 + 2) * 16 + c] + v[3] * wl[(i * 4 + 3) * 16 + c];
    }
    out[idx] = acc;
}

extern "C" void kernel_launch(void* const* d_in, const int* in_sizes, int n_in,
                              void* d_out, int out_size, void* d_ws, size_t ws_size,
                              hipStream_t stream)
{
    const void* x    = d_in[0];
    const int*  ei   = (const int*)d_in[2];
    const void* liw  = d_in[3];
    const void* lib  = d_in[4];
    const void* w0   = d_in[5];
    const void* b0   = d_in[6];
    const void* w1   = d_in[7];
    const void* b1   = d_in[8];
    const void* w2   = d_in[9];
    const void* b2   = d_in[10];
    const void* low  = d_in[11];
    const void* lob  = d_in[12];
    float* out = (float*)d_out;

    // ws (~36.2 MB, under proven 38.7 MB)
    char* wp = (char*)d_ws;
    int*   flags  = (int*)wp;                 wp += 256;
    float* hA     = (float*)wp;               wp += (size_t)N_NODES * D_HID * 4;
    f16*   Psrc   = (f16*)wp;                 wp += ((size_t)N_NODES + 1) * D_HID * 2;  // +1 dummy -inf row
    f16*   Pdst   = (f16*)wp;                 wp += (size_t)N_NODES * D_HID * 2;
    f16*   wfrag  = (f16*)wp;                 wp += (size_t)4 * 32 * 64 * 8 * 2;  // 128 KB
    float* cpad   = (float*)wp;               wp += (size_t)4 * 64 * 4;           // 1 KB
    int*   cursor = (int*)wp;                 wp += (size_t)N_NODES * 4;          // degree
    int*   bsum_t = (int*)wp;                 wp += 256 * 4;
    int*   boff_t = (int*)wp;                 wp += 256 * 4;
    int*   tmeta  = (int*)wp;                 wp += (size_t)TMAX * 4;
    unsigned short* slots = (unsigned short*)wp; wp += (size_t)N_NODES * SCAP * 2; // 4.8 MB
    int*   toff   = (int*)wp;                 wp += ((size_t)N_NODES + 4) * 4;
    int*   gbcnt  = (int*)wp;                 wp += 128 * 4;
    unsigned int* gbuckets = (unsigned int*)wp; // NB*BCAP*4 = 4.8 MB

    // flags + Psrc dummy row + gbcnt zero (1 block)
    k_detect<<<1, 256, 0, stream>>>((const unsigned short*)x, ei, flags,
                                    gbcnt, (unsigned short*)Psrc);
    // fused: wprep (32) + phase-1 bucket scatter (GE8) + lin_in (GH) + cpad (1)
    k_prep<<<32 + GE8 + GH + 1, 256, 0, stream>>>(flags, w0, w1, w2, wfrag,
                                                  ei, gbcnt, gbuckets,
                                                  x, liw, lib, hA, b1, b2, cpad);
    // phase-2: LDS-local slot build + degrees + chunk tile sums
    k_bucket<<<NB, 256, 0, stream>>>(gbcnt, gbuckets, slots, cursor, bsum_t);

    k_scan2<<<1, 256, 0, stream>>>(bsum_t, boff_t, toff + N_NODES);
    k_scan3<<<NCHUNK, 256, 0, stream>>>(cursor, boff_t, toff, tmeta);

    for (int k = 0; k < 4; k++) {
        k_proj<<<(N_NODES / 16 + 3) / 4, 256, 0, stream>>>(flags, hA, wfrag, b0,
                                                           cursor, Psrc, Pdst, k);
        k_edge_tile<<<2048, 256, 0, stream>>>(flags, slots, tmeta, toff,
                                              Psrc, Pdst, hA, wfrag, b1, b2,
                                              cpad, k);
    }

    k_lin_out<<<(N_NODES * D_OUT + 255) / 256, 256, 0, stream>>>(flags, hA, low, lob, out);
}

// Round 9
// 392.679 us; speedup vs baseline: 1.0920x; 1.0920x over previous
//
#include <hip/hip_runtime.h>
#include <hip/hip_bf16.h>

#define N_NODES 50000
#define N_EDGES 800000
#define D_IN    16
#define D_HID   64
#define D_OUT   16
#define NCHUNK  ((N_NODES + 255) / 256)   // 196 scan chunks
#define TMAX    100352                    // >= worst-case padded tile count
#define GE8     ((N_EDGES / 8 + 255) / 256)      // 391 blocks (8 edges/thread)
#define GH      ((N_NODES * D_HID + 255) / 256)  // 12500 blocks
#define SCAP    48                        // slots per node (3 tiles)
#define NB      98                        // scatter buckets (512 nodes each)
#define BCAP    12288                     // edges per bucket capacity

typedef __hip_bfloat16 bf16;
typedef _Float16 f16;
typedef _Float16 f16x8 __attribute__((ext_vector_type(8)));
typedef _Float16 f16x4 __attribute__((ext_vector_type(4)));
typedef float    f32x4 __attribute__((ext_vector_type(4)));
typedef _Float16 f16x8a __attribute__((ext_vector_type(8), may_alias));
typedef _Float16 f16x4a __attribute__((ext_vector_type(4), may_alias));
typedef unsigned short u16x8a __attribute__((ext_vector_type(8), may_alias));
typedef float    f32x4a __attribute__((ext_vector_type(4), may_alias));

__device__ __forceinline__ float b2f(bf16 v) { return __bfloat162float(v); }
__device__ __forceinline__ float bfb(unsigned short u) {
    union { unsigned u; float f; } z; z.u = (unsigned)u << 16; return z.f;
}
__device__ __forceinline__ int clampn(int v) {
    return v < 0 ? 0 : (v >= N_NODES ? N_NODES - 1 : v);
}
__device__ __forceinline__ float rdf(const void* p, long i, int isbf) {
    return isbf ? b2f(((const bf16*)p)[i]) : ((const float*)p)[i];
}
__device__ __forceinline__ f16x8 relu8(f16x8 v) {
#pragma unroll
    for (int j = 0; j < 8; j++) v[j] = v[j] > (f16)0 ? v[j] : (f16)0;
    return v;
}
__device__ __forceinline__ f16x4 relu4(f16x4 v) {
#pragma unroll
    for (int j = 0; j < 4; j++) v[j] = v[j] > (f16)0 ? v[j] : (f16)0;
    return v;
}
// tile slot base (u16 element index) from packed tmeta (n | valid<<20 | j<<25)
__device__ __forceinline__ int sbase(int m) {
    return (m & 0xFFFFF) * SCAP + ((m >> 25) & 3) * 16;
}

// ---------------------------------------------------------------------------
// k_detect (1 block): dtype flags + Psrc dummy -inf row + zero bucket cnts.
// ---------------------------------------------------------------------------
__global__ __launch_bounds__(256) void k_detect(const unsigned short* __restrict__ xw,
                                                const int* __restrict__ ei,
                                                int* __restrict__ flags,
                                                int* __restrict__ gbcnt,
                                                unsigned short* __restrict__ psrc_us)
{
    const int t = threadIdx.x;
    if (t < 64) psrc_us[(size_t)N_NODES * 64 + t] = 0xFC00u;   // f16 -inf
    if (t < NB) gbcnt[t] = 0;
    if (t == 0) {
        int inband = 0;
        for (int j = 0; j < 256; j++) {
            unsigned short w = xw[2 * j];
            int e = (w >> 7) & 0xFF;
            if ((w & 0x7FFF) == 0 || (e >= 100 && e <= 140)) inband++;
        }
        flags[0] = (inband >= 192) ? 1 : 0;
        int z = 1;
        for (int j = 1; j < 128; j += 2) z &= (ei[j] == 0) ? 1 : 0;
        flags[1] = z;
    }
}

// ---------------------------------------------------------------------------
// Fused prep (R25-verified): wprep + bucketed phase-1 scatter + lin_in + cpad
// ---------------------------------------------------------------------------
__global__ __launch_bounds__(256) void k_prep(const int* __restrict__ flags,
                                              const void* __restrict__ gw0,
                                              const void* __restrict__ gw1,
                                              const void* __restrict__ gw2,
                                              f16* __restrict__ wfrag,
                                              const int* __restrict__ eidx,
                                              int* __restrict__ gbcnt,
                                              unsigned int* __restrict__ gbuckets,
                                              const void* __restrict__ x,
                                              const void* __restrict__ liw,
                                              const void* __restrict__ lib,
                                              float* __restrict__ h,
                                              const void* __restrict__ gb1,
                                              const void* __restrict__ gb2,
                                              float* __restrict__ cpad)
{
    const int isbf = flags[0];
    const int bid = blockIdx.x;
    if (bid < 32) {
        // ---- weight prep ----
        int idx = bid * 256 + threadIdx.x;      // [0, 8192)
        int kb = idx >> 11, rem = idx & 2047;
        int slot = rem >> 6, lane = rem & 63;
        int lm = lane & 15, quad = lane >> 4;
        f16* outp = wfrag + (long)idx * 8;
        if (slot < 16) {
            int c = slot >> 2, q = slot & 3;
            long base = (long)kb * 2 * D_HID * D_HID;
#pragma unroll
            for (int j = 0; j < 8; j++)
                outp[j] = (f16)rdf(gw0, base + (long)(c * 32 + quad * 8 + j) * 64 + q * 16 + lm, isbf);
        } else {
            const void* gw = (slot < 24) ? gw1 : gw2;
            int s = (slot < 24) ? slot - 16 : slot - 24;
            int c = s >> 2, q = s & 3;
            long base = (long)kb * D_HID * D_HID;
#pragma unroll
            for (int j = 0; j < 8; j++)
                outp[j] = (f16)rdf(gw, base + (long)(c * 32 + quad * 8 + j) * 64 + q * 16 + lm, isbf);
        }
    } else if (bid < 32 + GE8) {
        // ---- phase-1 bucket scatter (NO early return: block barriers) ----
        __shared__ int cnt[NB], base[NB];
        const int t = threadIdx.x;
        for (int k = t; k < NB; k += 256) cnt[k] = 0;
        __syncthreads();
        const int ebase = ((bid - 32) * 256 + t) * 8;
        const int cntv = (ebase < N_EDGES) ? min(8, N_EDGES - ebase) : 0;
        const int strd = flags[1] ? 2 : 1;
        const long dbase = flags[1] ? (long)(2 * N_EDGES) : (long)N_EDGES;
        int d[8], s[8], r[8];
#pragma unroll
        for (int j = 0; j < 8; j++)
            if (j < cntv) {
                d[j] = clampn(eidx[dbase + (long)(ebase + j) * strd]);
                s[j] = clampn(eidx[(long)(ebase + j) * strd]);
            }
#pragma unroll
        for (int j = 0; j < 8; j++)
            if (j < cntv) r[j] = atomicAdd(&cnt[d[j] >> 9], 1);
        __syncthreads();
        for (int k = t; k < NB; k += 256)
            base[k] = cnt[k] ? atomicAdd(&gbcnt[k], cnt[k]) : 0;
        __syncthreads();
#pragma unroll
        for (int j = 0; j < 8; j++)
            if (j < cntv) {
                int b = d[j] >> 9;
                int p = base[b] + r[j];
                if (p < BCAP)
                    gbuckets[(size_t)b * BCAP + p] =
                        ((unsigned)(d[j] & 511) << 16) | (unsigned)s[j];
            }
    } else if (bid < 32 + GE8 + GH) {
        // ---- lin_in (vectorized) ----
        int idx = (bid - 32 - GE8) * 256 + threadIdx.x;
        if (idx >= N_NODES * D_HID) return;
        int n = idx >> 6, c = idx & 63;
        float acc, wr[16], xr[16];
        if (isbf) {
            const unsigned short* xp = (const unsigned short*)x + (long)n * 16;
            u16x8a x0 = *(const u16x8a*)xp, x1 = *(const u16x8a*)(xp + 8);
#pragma unroll
            for (int i = 0; i < 8; i++) { xr[i] = bfb(x0[i]); xr[8 + i] = bfb(x1[i]); }
            const unsigned short* wq = (const unsigned short*)liw;
#pragma unroll
            for (int i = 0; i < 16; i++) wr[i] = bfb(wq[i * 64 + c]);
            acc = bfb(((const unsigned short*)lib)[c]);
        } else {
            const float* xp = (const float*)x + (long)n * 16;
#pragma unroll
            for (int q = 0; q < 4; q++) {
                f32x4a v = *(const f32x4a*)(xp + q * 4);
#pragma unroll
                for (int j = 0; j < 4; j++) xr[q * 4 + j] = v[j];
            }
            const float* wq = (const float*)liw;
#pragma unroll
            for (int i = 0; i < 16; i++) wr[i] = wq[i * 64 + c];
            acc = ((const float*)lib)[c];
        }
#pragma unroll
        for (int i = 0; i < 16; i++) acc += xr[i] * wr[i];
        h[idx] = acc;
    } else {
        // ---- c_pad: mirror the f16 MFMA quantization path exactly ----
        int t = threadIdx.x;                  // 256 = 4 kblk x 64 feats
        int k = t >> 6, j = t & 63;
        float acc = rdf(gb2, (long)k * 64 + j, isbf);
        for (int i = 0; i < 64; i++) {
            float zi = (float)(f16)fmaxf(rdf(gb1, (long)k * 64 + i, isbf), 0.f);
            float wi = (float)(f16)rdf(gw2, (long)k * 4096 + (long)i * 64 + j, isbf);
            acc += zi * wi;
        }
        cpad[k * 64 + j] = acc;
    }
}

// ---------------------------------------------------------------------------
// phase-2: per-bucket LDS slot build + degrees + chunk tile sums.
// ---------------------------------------------------------------------------
__global__ __launch_bounds__(256) void k_bucket(const int* __restrict__ gbcnt,
                                                const unsigned int* __restrict__ gbuckets,
                                                unsigned short* __restrict__ slots,
                                                int* __restrict__ deg,
                                                int* __restrict__ bsum_t)
{
    __shared__ unsigned short sl[512 * SCAP];   // 49152 B
    __shared__ int cur[512];
    __shared__ int red[256];
    const int t = threadIdx.x, b = blockIdx.x;

    for (int k = t; k < 512; k += 256) cur[k] = 0;
    unsigned int* sl32 = (unsigned int*)sl;
    for (int k = t; k < 512 * SCAP / 2; k += 256) sl32[k] = 0xC350C350u;  // dummy id
    __syncthreads();

    const int ne = min(gbcnt[b], BCAP);
    const unsigned int* eb = gbuckets + (size_t)b * BCAP;
    for (int k = t; k < ne; k += 256) {
        unsigned int rec = eb[k];
        int n = rec >> 16;
        int pos = atomicAdd(&cur[n], 1);
        if (pos < SCAP) sl[n * SCAP + pos] = (unsigned short)(rec & 0xFFFFu);
    }
    __syncthreads();

    const int n0 = b * 512;
    const int nn = min(512, N_NODES - n0);
    // coalesced slot writeout (u32)
    unsigned int* gs32 = (unsigned int*)slots;
    for (int k = t; k < nn * SCAP / 2; k += 256)
        gs32[(size_t)n0 * SCAP / 2 + k] = sl32[k];
    // degrees + per-chunk tile sums (2 chunks of 256 nodes per bucket)
    for (int half = 0; half < 2; half++) {
        int n = half * 256 + t;
        int dv = (n < nn) ? cur[n] : 0;
        if (n < nn) deg[n0 + n] = dv;
        red[t] = min((dv + 15) >> 4, 3);
        __syncthreads();
        for (int d2 = 128; d2 > 0; d2 >>= 1) {
            if (t < d2) red[t] += red[t + d2];
            __syncthreads();
        }
        if (t == 0) bsum_t[b * 2 + half] = red[0];
        __syncthreads();
    }
}

__global__ __launch_bounds__(256) void k_scan2(const int* __restrict__ bsum_t,
                                               int* __restrict__ boff_t,
                                               int* __restrict__ tot_t)
{
    __shared__ int st_[256];
    const int t = threadIdx.x;
    st_[t] = (t < NCHUNK) ? bsum_t[t] : 0;
    __syncthreads();
    for (int d = 1; d < 256; d <<= 1) {
        int vt = (t >= d) ? st_[t - d] : 0;
        __syncthreads();
        st_[t] += vt;
        __syncthreads();
    }
    if (t < NCHUNK) boff_t[t] = (t == 0) ? 0 : st_[t - 1];
    if (t == NCHUNK - 1) tot_t[0] = st_[t];
}

// final scan stage + tmeta emission: tmeta[t] = node | valid<<20 | j<<25
__global__ __launch_bounds__(256) void k_scan3(const int* __restrict__ deg,
                                               const int* __restrict__ boff_t,
                                               int* __restrict__ toff,
                                               int* __restrict__ tmeta)
{
    __shared__ int st_[256];
    const int t = threadIdx.x;
    int i = blockIdx.x * 256 + t;
    int v = (i < N_NODES) ? deg[i] : 0;
    int w = min((v + 15) >> 4, 3);
    st_[t] = w;
    __syncthreads();
    for (int d = 1; d < 256; d <<= 1) {
        int ut = (t >= d) ? st_[t - d] : 0;
        __syncthreads();
        st_[t] += ut;
        __syncthreads();
    }
    if (i < N_NODES) {
        int exT = boff_t[blockIdx.x] + st_[t] - w;
        toff[i] = exT;
        for (int j = 0; j < w; j++)
            tmeta[exT + j] = i | (min(16, v - 16 * j) << 20) | (j << 25);
    }
}

// ---------------------------------------------------------------------------
// Node projection (R17-verified). Zero-in-degree nodes zeroed here.
// ---------------------------------------------------------------------------
#define HP_ST 72

__global__ __launch_bounds__(256) void k_proj(
    const int* __restrict__ flags, float* hio,
    const f16* __restrict__ wfrag, const void* __restrict__ gb0,
    const int* __restrict__ deg,
    f16* __restrict__ psrc, f16* __restrict__ pdst, int kblk)
{
    __shared__ f16 hL_s[4][16 * HP_ST];     // 9216 B

    const int tid  = threadIdx.x;
    const int isbf = flags[0];
    const int wv = tid >> 6, ln = tid & 63;
    const int lm = ln & 15, quad = ln >> 4;
    f16* hL = hL_s[wv];

    const int g = blockIdx.x * 4 + wv;
    if (g >= N_NODES / 16) return;
    const int n0 = g * 16;

    const f16* wb = wfrag + (long)kblk * 32 * 64 * 8;

#pragma unroll
    for (int i = 0; i < 16; i++) {
        int idx = i * 64 + ln;
        hL[(idx >> 6) * HP_ST + (idx & 63)] = (f16)hio[(long)n0 * 64 + idx];
    }
    // zero-in-degree nodes are never stored by the aggregation — zero their
    // rows so next proj / lin_out read segment_sum = 0
#pragma unroll
    for (int i = 0; i < 16; i++)
        if (deg[n0 + i] == 0) hio[(long)(n0 + i) * 64 + ln] = 0.f;

    f16x8 a[2];
#pragma unroll
    for (int c = 0; c < 2; c++)
        a[c] = *(const f16x8a*)&hL[lm * HP_ST + c * 32 + quad * 8];

    f32x4 accS[4], accD[4];
#pragma unroll
    for (int q = 0; q < 4; q++) {
        float bd = rdf(gb0, (long)kblk * 64 + q * 16 + lm, isbf);
        accS[q] = (f32x4){0.f, 0.f, 0.f, 0.f};
        accD[q] = (f32x4){bd, bd, bd, bd};
    }
#pragma unroll
    for (int c = 0; c < 2; c++)
#pragma unroll
        for (int q = 0; q < 4; q++) {
            f16x8 bs = *(const f16x8a*)&wb[(((c + 0) * 4 + q) * 64 + ln) * 8];
            f16x8 bd = *(const f16x8a*)&wb[(((c + 2) * 4 + q) * 64 + ln) * 8];
            accS[q] = __builtin_amdgcn_mfma_f32_16x16x32_f16(a[c], bs, accS[q], 0, 0, 0);
            accD[q] = __builtin_amdgcn_mfma_f32_16x16x32_f16(a[c], bd, accD[q], 0, 0, 0);
        }
#pragma unroll
    for (int q = 0; q < 4; q++)
#pragma unroll
        for (int r = 0; r < 4; r++) {
            long o = (long)(n0 + quad * 4 + r) * 64 + q * 16 + lm;
            psrc[o] = (f16)accS[q][r];
            pdst[o] = (f16)accD[q][r];
        }
}

// ---------------------------------------------------------------------------
// ROUND-27 aggregation (resubmit — R8 was an infra failure, kernel never ran):
// REGISTER-DIRECT GATHER. Layer1's operand-swapped B-fragment needs lane
// (lm,quad) to hold y[edge=lm][c*32+quad*8..+8]; the gather produces that
// layout DIRECTLY: lane (lm,quad) loads psrc[slot[lm]] at offsets quad*8 and
// 32+quad*8, adds broadcast pdst[n] fragment, relu -> a1 in registers.
// Layer0's LDS write AND the a1 LDS read are DELETED (2 of 3 LDS round trips
// in the per-tile chain). Same gather bytes (2KB/tile, re-laned). Pad algebra
// unchanged: pad column -> B-col 0 -> contributes relu(b1)@W2 = cp - b2,
// exactly the R24 flush correction. Only layer1->layer2 transpose keeps LDS.
// ---------------------------------------------------------------------------
#define Y_ST 72

__global__ __launch_bounds__(256) void k_edge_tile(
    const int* __restrict__ flags,
    const unsigned short* __restrict__ slots, const int* __restrict__ tmeta,
    const int* __restrict__ toff,
    const f16* __restrict__ psrc, const f16* __restrict__ pdst,
    float* __restrict__ hout,
    const f16* __restrict__ wfrag, const void* __restrict__ gb1,
    const void* __restrict__ gb2, const float* __restrict__ cpad, int kblk)
{
    __shared__ f16 y_s[4][16 * Y_ST];     // 9216 B
    __shared__ float b1L[64], b2L[64], cpL[64];

    const int tid  = threadIdx.x;
    const int isbf = flags[0];
    const int wv = tid >> 6, ln = tid & 63;
    const int lm = ln & 15, quad = ln >> 4;
    f16* y = y_s[wv];

    // stage biases + cpad (once per block)
    if (tid < 64)       b1L[tid]       = rdf(gb1, (long)kblk * 64 + tid, isbf);
    else if (tid < 128) b2L[tid - 64]  = rdf(gb2, (long)kblk * 64 + (tid - 64), isbf);
    else if (tid < 192) cpL[tid - 128] = cpad[kblk * 64 + (tid - 128)];
    __syncthreads();

    const f16* wb = wfrag + (long)kblk * 32 * 64 * 8;
    f16x8 bw1[2][4], bw2[2][4];
#pragma unroll
    for (int c = 0; c < 2; c++)
#pragma unroll
        for (int q = 0; q < 4; q++) {
            bw1[c][q] = *(const f16x8a*)&wb[((16 + c * 4 + q) * 64 + ln) * 8];
            bw2[c][q] = *(const f16x8a*)&wb[((24 + c * 4 + q) * 64 + ln) * 8];
        }

    const int T  = toff[N_NODES];
    const int W  = gridDim.x * 4;
    const int gw = blockIdx.x * 4 + wv;
    int t0 = (int)((long)gw * T / W);
    int t1 = (int)((long)(gw + 1) * T / W);
    // node-aligned ownership (exact partition of [0, T))
    if (t0 > 0)
        while (t0 < T && (tmeta[t0] & 0xFFFFF) == (tmeta[t0 - 1] & 0xFFFFF)) t0++;
    if (t1 > 0)
        while (t1 < T && (tmeta[t1] & 0xFFFFF) == (tmeta[t1 - 1] & 0xFFFFF)) t1++;
    if (t0 >= t1) return;

    // ---- pipeline prologue: meta t0..t0+2, slot t0..t0+1, data t0 ----
    int mA = tmeta[t0];
    int mB = tmeta[min(t0 + 1, T - 1)];
    int mC = tmeta[min(t0 + 2, T - 1)];
    int sA = slots[sbase(mA) + lm];
    int sB = slots[sbase(mB) + lm];
    f16x8 psA0 = *(const f16x8a*)&psrc[(long)sA * 64 + quad * 8];
    f16x8 psA1 = *(const f16x8a*)&psrc[(long)sA * 64 + 32 + quad * 8];
    f16x8 pdA0 = *(const f16x8a*)&pdst[(long)(mA & 0xFFFFF) * 64 + quad * 8];
    f16x8 pdA1 = *(const f16x8a*)&pdst[(long)(mA & 0xFFFFF) * 64 + 32 + quad * 8];

    f32x4 accv[4];
#pragma unroll
    for (int q = 0; q < 4; q++) accv[q] = (f32x4){0.f, 0.f, 0.f, 0.f};

    for (int tt = t0; tt < t1; ++tt) {
        // ---- prefetch meta tt+3, slot tt+2, data tt+1 ----
        const int mD = tmeta[min(tt + 3, T - 1)];
        const int sC = slots[sbase(mC) + lm];
        f16x8 psB0 = *(const f16x8a*)&psrc[(long)sB * 64 + quad * 8];
        f16x8 psB1 = *(const f16x8a*)&psrc[(long)sB * 64 + 32 + quad * 8];
        f16x8 pdB0 = *(const f16x8a*)&pdst[(long)(mB & 0xFFFFF) * 64 + quad * 8];
        f16x8 pdB1 = *(const f16x8a*)&pdst[(long)(mB & 0xFFFFF) * 64 + 32 + quad * 8];

        // ---- layer 0+1 input fused IN REGISTERS (no LDS round trip):
        //      a1 = relu(ps + pd) IS the layer1 B-fragment directly ----
        f16x8 a1_0 = relu8(psA0 + pdA0);
        f16x8 a1_1 = relu8(psA1 + pdA1);

        f32x4 acc1[4];
#pragma unroll
        for (int q = 0; q < 4; q++)
            acc1[q] = *(const f32x4a*)&b1L[q * 16 + quad * 4];
#pragma unroll
        for (int q = 0; q < 4; q++)
            acc1[q] = __builtin_amdgcn_mfma_f32_16x16x32_f16(bw1[0][q], a1_0, acc1[q], 0, 0, 0);
#pragma unroll
        for (int q = 0; q < 4; q++)
            acc1[q] = __builtin_amdgcn_mfma_f32_16x16x32_f16(bw1[1][q], a1_1, acc1[q], 0, 0, 0);

        // transposed output D[n][e=lm] -> packed b64 writes to y[e=lm][n]
#pragma unroll
        for (int q = 0; q < 4; q++) {
            f16x4 pk = { (f16)acc1[q][0], (f16)acc1[q][1],
                         (f16)acc1[q][2], (f16)acc1[q][3] };
            *(f16x4a*)&y[lm * Y_ST + q * 16 + quad * 4] = relu4(pk);
        }

        // ---- layer 2 (a2 via single LDS transpose hop; accumulate in C) ----
        f16x8 a2_0 = *(const f16x8a*)&y[lm * Y_ST + quad * 8];
        f16x8 a2_1 = *(const f16x8a*)&y[lm * Y_ST + 32 + quad * 8];
#pragma unroll
        for (int q = 0; q < 4; q++)
            accv[q] = __builtin_amdgcn_mfma_f32_16x16x32_f16(a2_0, bw2[0][q], accv[q], 0, 0, 0);
#pragma unroll
        for (int q = 0; q < 4; q++)
            accv[q] = __builtin_amdgcn_mfma_f32_16x16x32_f16(a2_1, bw2[1][q], accv[q], 0, 0, 0);

        // ---- flush when node changes (plain store: node owned by wave) ----
        const int curn = mA & 0xFFFFF;
        const int nxt  = (tt + 1 < t1) ? (mB & 0xFFFFF) : -1;
        if (nxt != curn) {
            const float npad = (float)(16 - ((mA >> 20) & 31));  // pads only in last tile
            const float nt16 = (float)((((mA >> 25) & 3) + 1) * 16);
#pragma unroll
            for (int q = 0; q < 4; q++) {
                float v = accv[q][0] + accv[q][1] + accv[q][2] + accv[q][3];
                v += __shfl_xor(v, 16, 64);
                v += __shfl_xor(v, 32, 64);
                if (quad == 0) {
                    const int f = q * 16 + lm;
                    hout[(long)curn * 64 + f] = v + nt16 * b2L[f] - npad * cpL[f];
                }
                accv[q] = (f32x4){0.f, 0.f, 0.f, 0.f};
            }
        }

        // ---- rotate pipeline ----
        mA = mB; mB = mC; mC = mD;
        sB = sC;
        psA0 = psB0; psA1 = psB1; pdA0 = pdB0; pdA1 = pdB1;
    }
}

// ---------------------------------------------------------------------------
// lin_out: W/b staged in LDS once per block, float4 h loads.
// ---------------------------------------------------------------------------
__global__ __launch_bounds__(256) void k_lin_out(const int* __restrict__ flags,
                                                 const float* __restrict__ h,
                                                 const void* __restrict__ w,
                                                 const void* __restrict__ b,
                                                 float* __restrict__ out)
{
    __shared__ float wl[D_HID * D_OUT];   // 4 KB
    __shared__ float bl[D_OUT];
    const int isbf = flags[0];
    const int t = threadIdx.x;
    for (int k = t; k < D_HID * D_OUT; k += 256) wl[k] = rdf(w, k, isbf);
    if (t < D_OUT) bl[t] = rdf(b, t, isbf);
    __syncthreads();

    int idx = blockIdx.x * 256 + t;
    if (idx >= N_NODES * D_OUT) return;
    int n = idx >> 4, c = idx & 15;
    const float* hr = h + (long)n * D_HID;
    float acc = bl[c];
#pragma unroll
    for (int i = 0; i < 16; i++) {
        f32x4a v = *(const f32x4a*)(hr + i * 4);
        acc += v[0] * wl[(i * 4 + 0) * 16 + c] + v[1] * wl[(i * 4 + 1) * 16 + c]
             + v[2] * wl[(i * 4 + 2) * 16 + c] + v[3] * wl[(i * 4 + 3) * 16 + c];
    }
    out[idx] = acc;
}

extern "C" void kernel_launch(void* const* d_in, const int* in_sizes, int n_in,
                              void* d_out, int out_size, void* d_ws, size_t ws_size,
                              hipStream_t stream)
{
    const void* x    = d_in[0];
    const int*  ei   = (const int*)d_in[2];
    const void* liw  = d_in[3];
    const void* lib  = d_in[4];
    const void* w0   = d_in[5];
    const void* b0   = d_in[6];
    const void* w1   = d_in[7];
    const void* b1   = d_in[8];
    const void* w2   = d_in[9];
    const void* b2   = d_in[10];
    const void* low  = d_in[11];
    const void* lob  = d_in[12];
    float* out = (float*)d_out;

    // ws (~36.2 MB, under proven 38.7 MB)
    char* wp = (char*)d_ws;
    int*   flags  = (int*)wp;                 wp += 256;
    float* hA     = (float*)wp;               wp += (size_t)N_NODES * D_HID * 4;
    f16*   Psrc   = (f16*)wp;                 wp += ((size_t)N_NODES + 1) * D_HID * 2;  // +1 dummy -inf row
    f16*   Pdst   = (f16*)wp;                 wp += (size_t)N_NODES * D_HID * 2;
    f16*   wfrag  = (f16*)wp;                 wp += (size_t)4 * 32 * 64 * 8 * 2;  // 128 KB
    float* cpad   = (float*)wp;               wp += (size_t)4 * 64 * 4;           // 1 KB
    int*   cursor = (int*)wp;                 wp += (size_t)N_NODES * 4;          // degree
    int*   bsum_t = (int*)wp;                 wp += 256 * 4;
    int*   boff_t = (int*)wp;                 wp += 256 * 4;
    int*   tmeta  = (int*)wp;                 wp += (size_t)TMAX * 4;
    unsigned short* slots = (unsigned short*)wp; wp += (size_t)N_NODES * SCAP * 2; // 4.8 MB
    int*   toff   = (int*)wp;                 wp += ((size_t)N_NODES + 4) * 4;
    int*   gbcnt  = (int*)wp;                 wp += 128 * 4;
    unsigned int* gbuckets = (unsigned int*)wp; // NB*BCAP*4 = 4.8 MB

    // flags + Psrc dummy row + gbcnt zero (1 block)
    k_detect<<<1, 256, 0, stream>>>((const unsigned short*)x, ei, flags,
                                    gbcnt, (unsigned short*)Psrc);
    // fused: wprep (32) + phase-1 bucket scatter (GE8) + lin_in (GH) + cpad (1)
    k_prep<<<32 + GE8 + GH + 1, 256, 0, stream>>>(flags, w0, w1, w2, wfrag,
                                                  ei, gbcnt, gbuckets,
                                                  x, liw, lib, hA, b1, b2, cpad);
    // phase-2: LDS-local slot build + degrees + chunk tile sums
    k_bucket<<<NB, 256, 0, stream>>>(gbcnt, gbuckets, slots, cursor, bsum_t);

    k_scan2<<<1, 256, 0, stream>>>(bsum_t, boff_t, toff + N_NODES);
    k_scan3<<<NCHUNK, 256, 0, stream>>>(cursor, boff_t, toff, tmeta);

    for (int k = 0; k < 4; k++) {
        k_proj<<<(N_NODES / 16 + 3) / 4, 256, 0, stream>>>(flags, hA, wfrag, b0,
                                                           cursor, Psrc, Pdst, k);
        k_edge_tile<<<2048, 256, 0, stream>>>(flags, slots, tmeta, toff,
                                              Psrc, Pdst, hA, wfrag, b1, b2,
                                              cpad, k);
    }

    k_lin_out<<<(N_NODES * D_OUT + 255) / 256, 256, 0, stream>>>(flags, hA, low, lob, out);
}